// Round 4
// baseline (2112.012 us; speedup 1.0000x reference)
//
#include <hip/hip_runtime.h>

// ---------------- constants ----------------
#define BB    32
#define SS    512
#define DD    1024
#define HH_   16
#define DH    64
#define LL    4
#define DFF   2048
#define DMEM  512
#define NTOK  (BB * SS)          // 16384
#define SPLD  74                 // padded LDS row stride (u16) for attn

typedef __attribute__((ext_vector_type(8))) short short8;
typedef __attribute__((ext_vector_type(4))) float f32x4;

__device__ __forceinline__ unsigned short f2bf(float x) {
    unsigned u = __float_as_uint(x);
    u = (u + 0x7FFFu + ((u >> 16) & 1u)) >> 16;   // RNE fp32->bf16
    return (unsigned short)u;
}
__device__ __forceinline__ float bf2f(unsigned short x) {
    return __uint_as_float(((unsigned)x) << 16);
}

// async global->LDS, 16 bytes per lane; LDS dest = wave-uniform base + lane*16
__device__ __forceinline__ void async16(const unsigned short* g, unsigned short* l) {
    __builtin_amdgcn_global_load_lds(
        (__attribute__((address_space(1))) void*)g,
        (__attribute__((address_space(3))) void*)l,
        16, 0, 0);
}

// ---------------- fp32 -> bf16 convert (vectorized x4) ----------------
__global__ void cvt_bf16(const float* __restrict__ in, unsigned short* __restrict__ out, int n) {
    int i4 = (blockIdx.x * 256 + threadIdx.x) * 4;
    if (i4 < n) {
        float4 v = *(const float4*)&in[i4];
        uint2 pk;
        pk.x = f2bf(v.x) | ((unsigned)f2bf(v.y) << 16);
        pk.y = f2bf(v.z) | ((unsigned)f2bf(v.w) << 16);
        *(uint2*)&out[i4] = pk;
    }
}

// ---------------- h = x + PE -> bf16 residual stream (vectorized x4) ----------------
__global__ void add_pe_kernel(const float* __restrict__ x,
                              unsigned short* __restrict__ hb) {
    int i4 = (blockIdx.x * 256 + threadIdx.x) * 4;   // 16M elems / 4
    int d = i4 & (DD - 1);                           // multiple of 4
    int t = i4 >> 10;
    int s = t & (SS - 1);
    const float c = -9.210340371976184f / (float)DD;
    float f0 = __expf((float)d * c);
    float f2 = __expf((float)(d + 2) * c);
    float a0 = (float)s * f0, a2 = (float)s * f2;
    float4 xv = *(const float4*)&x[i4];
    uint2 pk;
    pk.x = f2bf(xv.x + __sinf(a0)) | ((unsigned)f2bf(xv.y + __cosf(a0)) << 16);
    pk.y = f2bf(xv.z + __sinf(a2)) | ((unsigned)f2bf(xv.w + __cosf(a2)) << 16);
    *(uint2*)&hb[i4] = pk;
}

// ================== 256x256 8-phase GEMM (T2+T3/T4+T5), bf16 weights ==================
// C[M,N] = A[M,K] * W[N,K]^T + bias. 512 threads = 8 waves (2M x 4N), per-wave 128x64.
// BK=64 per K-tile, 2 K-tiles (buf0/buf1) double-buffered = 128 KiB LDS.
// Staging: global_load_lds, linear LDS dest, INVERSE-swizzled global source;
// reads XOR-swizzle the 16B chunk index by (row&7) -> conflict-free per 8-lane phase.
// vmcnt(4) only at phase D (once per K-tile); setprio(1) around MFMA clusters.
#define BAR   __builtin_amdgcn_s_barrier()
#define LGKM0 do { asm volatile("s_waitcnt lgkmcnt(0)" ::: "memory"); \
                   __builtin_amdgcn_sched_barrier(0); } while (0)
#define VMC4  asm volatile("s_waitcnt vmcnt(4)" ::: "memory")

// stage one 128-row half-tile (2 x global_load_lds per wave):
// OP: 0=A, 1=W. rows (HALF*128 + wid*16 .. +15), global chunk = (lane&7)^(lane>>3)
#define STAGE(BUF, OP, HALFI, KS) do {                                          \
    const unsigned short* _g = (OP) ? Wb : A;                                   \
    const size_t _gr = ((OP) ? Brow0 : Arow0) + (HALFI) * 128 + wid * 16 + l8;  \
    unsigned short* _d = &lds[BUF][OP][(((HALFI) * 128 + wid * 16)) * 64];      \
    const int _ks = (KS);                                                       \
    async16(&_g[_gr * (size_t)K + _ks + cl8], _d);                              \
    async16(&_g[(_gr + 8) * (size_t)K + _ks + cl8], _d + 8 * 64);               \
} while (0)

// one half-iteration = 4 phases computing K-tile in buf CUR while staging:
//  phA: read A[m0-3],B[n0-1](CUR); stage OTH.A half0 @KS1; mfma (m0-3 x n0-1)
//  phB: read B[n2-3];             stage OTH.A half1 @KS1; mfma (m0-3 x n2-3)
//  phC: read A[m4-7];             stage CUR.B half0 @KS2; mfma (m4-7 x n2-3)
//  phD: (no reads)                stage CUR.B half1 @KS2; vmcnt(4); mfma (m4-7 x n0-1)
#define HALF_ITER(CUR, OTH, KS1, KS2) {                                         \
    short8 afr[4][2], b01[2][2], b23[2][2];                                     \
    _Pragma("unroll") for (int m = 0; m < 4; m++) {                             \
        afr[m][0] = *(const short8*)&lds[CUR][0][aro + m * 1024 + cb0];         \
        afr[m][1] = *(const short8*)&lds[CUR][0][aro + m * 1024 + cb1]; }       \
    _Pragma("unroll") for (int n = 0; n < 2; n++) {                             \
        b01[n][0] = *(const short8*)&lds[CUR][1][bro + n * 1024 + cb0];         \
        b01[n][1] = *(const short8*)&lds[CUR][1][bro + n * 1024 + cb1]; }       \
    STAGE(OTH, 0, 0, KS1);                                                      \
    BAR; LGKM0;                                                                 \
    __builtin_amdgcn_s_setprio(1);                                              \
    _Pragma("unroll") for (int m = 0; m < 4; m++)                               \
        _Pragma("unroll") for (int n = 0; n < 2; n++) {                         \
            acc[m][n] = __builtin_amdgcn_mfma_f32_16x16x32_bf16(b01[n][0], afr[m][0], acc[m][n], 0, 0, 0); \
            acc[m][n] = __builtin_amdgcn_mfma_f32_16x16x32_bf16(b01[n][1], afr[m][1], acc[m][n], 0, 0, 0); } \
    __builtin_amdgcn_s_setprio(0);                                              \
    BAR;                                                                        \
    _Pragma("unroll") for (int n = 0; n < 2; n++) {                             \
        b23[n][0] = *(const short8*)&lds[CUR][1][bro + (n + 2) * 1024 + cb0];   \
        b23[n][1] = *(const short8*)&lds[CUR][1][bro + (n + 2) * 1024 + cb1]; } \
    STAGE(OTH, 0, 1, KS1);                                                      \
    BAR; LGKM0;                                                                 \
    __builtin_amdgcn_s_setprio(1);                                              \
    _Pragma("unroll") for (int m = 0; m < 4; m++)                               \
        _Pragma("unroll") for (int n = 0; n < 2; n++) {                         \
            acc[m][n + 2] = __builtin_amdgcn_mfma_f32_16x16x32_bf16(b23[n][0], afr[m][0], acc[m][n + 2], 0, 0, 0); \
            acc[m][n + 2] = __builtin_amdgcn_mfma_f32_16x16x32_bf16(b23[n][1], afr[m][1], acc[m][n + 2], 0, 0, 0); } \
    __builtin_amdgcn_s_setprio(0);                                              \
    BAR;                                                                        \
    _Pragma("unroll") for (int m = 0; m < 4; m++) {                             \
        afr[m][0] = *(const short8*)&lds[CUR][0][aro + (m + 4) * 1024 + cb0];   \
        afr[m][1] = *(const short8*)&lds[CUR][0][aro + (m + 4) * 1024 + cb1]; } \
    STAGE(CUR, 1, 0, KS2);                                                      \
    BAR; LGKM0;                                                                 \
    __builtin_amdgcn_s_setprio(1);                                              \
    _Pragma("unroll") for (int m = 0; m < 4; m++)                               \
        _Pragma("unroll") for (int n = 0; n < 2; n++) {                         \
            acc[m + 4][n + 2] = __builtin_amdgcn_mfma_f32_16x16x32_bf16(b23[n][0], afr[m][0], acc[m + 4][n + 2], 0, 0, 0); \
            acc[m + 4][n + 2] = __builtin_amdgcn_mfma_f32_16x16x32_bf16(b23[n][1], afr[m][1], acc[m + 4][n + 2], 0, 0, 0); } \
    __builtin_amdgcn_s_setprio(0);                                              \
    BAR;                                                                        \
    STAGE(CUR, 1, 1, KS2);                                                      \
    VMC4;                                                                       \
    BAR;                                                                        \
    __builtin_amdgcn_s_setprio(1);                                              \
    _Pragma("unroll") for (int m = 0; m < 4; m++)                               \
        _Pragma("unroll") for (int n = 0; n < 2; n++) {                         \
            acc[m + 4][n] = __builtin_amdgcn_mfma_f32_16x16x32_bf16(b01[n][0], afr[m][0], acc[m + 4][n], 0, 0, 0); \
            acc[m + 4][n] = __builtin_amdgcn_mfma_f32_16x16x32_bf16(b01[n][1], afr[m][1], acc[m + 4][n], 0, 0, 0); } \
    __builtin_amdgcn_s_setprio(0);                                              \
    BAR;                                                                        \
}

template<bool RELU>
__global__ __launch_bounds__(512, 2) void gemm_bt8(
    const unsigned short* __restrict__ A,
    const unsigned short* __restrict__ Wb,
    const float* __restrict__ bias,
    float* __restrict__ Cf, unsigned short* __restrict__ Cb,
    int M, int N, int K)
{
    __shared__ __align__(16) unsigned short lds[2][2][256 * 64];   // [buf][A/W][row*64+col]
    const int tid  = threadIdx.x;
    const int wid  = tid >> 6, lane = tid & 63;
    const int wm   = wid >> 2, wn = wid & 3;        // 2 x 4 wave grid
    const int quad = lane >> 4, l16 = lane & 15;
    const int l8   = lane >> 3;                     // staging: row within 8-row segment
    const int cl8  = (((lane & 7) ^ l8) & 7) * 8;   // staging: global chunk (u16 units)
    const int bm   = blockIdx.y, bn = blockIdx.x;
    const size_t Arow0 = (size_t)bm * 256, Brow0 = (size_t)bn * 256;

    // read-side swizzled column offsets (u16) for kk=0,1: chunk = (kk*4+quad) ^ (l16&7)
    const int swz = l16 & 7;
    const int cb0 = ((quad) ^ swz) * 8;
    const int cb1 = ((4 + quad) ^ swz) * 8;
    // per-wave row bases (u16 index): + m*1024 / n*1024 + cb
    const int aro = (wm * 128 + l16) * 64;
    const int bro = (wn * 64 + l16) * 64;

    f32x4 acc[8][4];
    #pragma unroll
    for (int i = 0; i < 8; i++)
        #pragma unroll
        for (int j = 0; j < 4; j++) acc[i][j] = (f32x4){0.f, 0.f, 0.f, 0.f};

    // ---- prologue: buf0 <- ktile 0 (B,B,A,A), buf1.B <- ktile 64; wait oldest 8 ----
    STAGE(0, 1, 0, 0);  STAGE(0, 1, 1, 0);
    STAGE(0, 0, 0, 0);  STAGE(0, 0, 1, 0);
    STAGE(1, 1, 0, 64); STAGE(1, 1, 1, 64);
    VMC4;
    BAR;

    for (int k0 = 0; k0 < K; k0 += 128) {
        const int ksb = (k0 + 128 < K) ? (k0 + 128) : (K - 64);  // buf0 refill ktile
        const int ksc = (k0 + 192 < K) ? (k0 + 192) : (K - 64);  // buf1 refill ktile
        HALF_ITER(0, 1, k0 + 64, ksb)
        HALF_ITER(1, 0, ksb, ksc)
    }

    // ---- epilogue (same fragment convention as verified m97 kernel) ----
    #pragma unroll
    for (int i = 0; i < 8; i++) {
        const size_t mrow = (size_t)(bm * 256 + wm * 128 + i * 16 + l16) * N;
        #pragma unroll
        for (int j = 0; j < 4; j++) {
            int n0 = bn * 256 + wn * 64 + j * 16 + quad * 4;
            f32x4 av = acc[i][j];
            float v[4];
            if (bias) {
                float4 bv = *(const float4*)&bias[n0];
                v[0] = av[0] + bv.x; v[1] = av[1] + bv.y;
                v[2] = av[2] + bv.z; v[3] = av[3] + bv.w;
            } else {
                v[0] = av[0]; v[1] = av[1]; v[2] = av[2]; v[3] = av[3];
            }
            if (RELU) {
                #pragma unroll
                for (int r = 0; r < 4; r++) v[r] = fmaxf(v[r], 0.f);
            }
            if (Cf) {
                float4 o4; o4.x = v[0]; o4.y = v[1]; o4.z = v[2]; o4.w = v[3];
                *(float4*)&Cf[mrow + n0] = o4;
            }
            if (Cb) {
                uint2 pk;
                pk.x = f2bf(v[0]) | ((unsigned)f2bf(v[1]) << 16);
                pk.y = f2bf(v[2]) | ((unsigned)f2bf(v[3]) << 16);
                *(uint2*)&Cb[mrow + n0] = pk;
            }
        }
    }
}

// ---------------- bf16 GEMM (m97 structure): fallback + N<1024 shapes ----------------
template<bool RELU, bool WPRE>
__global__ __launch_bounds__(256) void gemm_bt(
    const unsigned short* __restrict__ A,
    const unsigned short* __restrict__ Wb,
    const float* __restrict__ Wf,
    const float* __restrict__ bias,
    float* __restrict__ Cf, unsigned short* __restrict__ Cb,
    int M, int N, int K)
{
    __shared__ __align__(16) unsigned short As[128 * 32];
    __shared__ __align__(16) unsigned short Bs[128 * 32];
    const int tid  = threadIdx.x;
    const int bm   = blockIdx.y, bn = blockIdx.x;
    const int w    = tid >> 6, lane = tid & 63;
    const int wm   = (w >> 1) * 64, wn = (w & 1) * 64;
    const int quad = lane >> 4, l16 = lane & 15;

    f32x4 acc[4][4];
    #pragma unroll
    for (int i = 0; i < 4; i++)
        #pragma unroll
        for (int j = 0; j < 4; j++) acc[i][j] = (f32x4){0.f, 0.f, 0.f, 0.f};

    const int rlane = lane >> 2, clane = (lane & 3) * 8;

    for (int k0 = 0; k0 < K; k0 += 32) {
        __syncthreads();
        if (WPRE) {
            #pragma unroll
            for (int i = 0; i < 2; i++) {
                int j = w * 2 + i;
                async16(&A [(size_t)(bm * 128 + j * 16 + rlane) * K + k0 + clane], &As[j * 512]);
                async16(&Wb[(size_t)(bn * 128 + j * 16 + rlane) * K + k0 + clane], &Bs[j * 512]);
            }
        } else {
            #pragma unroll
            for (int u = 0; u < 2; u++) {
                int c = tid * 2 + u;
                int row = c >> 2, cc = (c & 3) * 8;
                *(uint4*)&As[row * 32 + cc] =
                    *(const uint4*)&A[(size_t)(bm * 128 + row) * K + k0 + cc];
                const float* wp = &Wf[(size_t)(bn * 128 + row) * K + k0 + cc];
                float4 w0 = *(const float4*)wp;
                float4 w1 = *(const float4*)(wp + 4);
                uint4 pk;
                pk.x = ((unsigned)f2bf(w0.y) << 16) | f2bf(w0.x);
                pk.y = ((unsigned)f2bf(w0.w) << 16) | f2bf(w0.z);
                pk.z = ((unsigned)f2bf(w1.y) << 16) | f2bf(w1.x);
                pk.w = ((unsigned)f2bf(w1.w) << 16) | f2bf(w1.z);
                *(uint4*)&Bs[row * 32 + cc] = pk;
            }
        }
        __syncthreads();
        short8 af[4], bfr[4];
        #pragma unroll
        for (int i = 0; i < 4; i++)
            af[i] = *(const short8*)&As[(wm + i * 16 + l16) * 32 + quad * 8];
        #pragma unroll
        for (int j = 0; j < 4; j++)
            bfr[j] = *(const short8*)&Bs[(wn + j * 16 + l16) * 32 + quad * 8];
        #pragma unroll
        for (int i = 0; i < 4; i++)
            #pragma unroll
            for (int j = 0; j < 4; j++)
                acc[i][j] = __builtin_amdgcn_mfma_f32_16x16x32_bf16(bfr[j], af[i], acc[i][j], 0, 0, 0);
    }

    #pragma unroll
    for (int i = 0; i < 4; i++) {
        const size_t mrow = (size_t)(bm * 128 + wm + i * 16 + l16) * N;
        #pragma unroll
        for (int j = 0; j < 4; j++) {
            int n0 = bn * 128 + wn + j * 16 + quad * 4;
            f32x4 av = acc[i][j];
            float v[4];
            if (bias) {
                float4 bv = *(const float4*)&bias[n0];
                v[0] = av[0] + bv.x; v[1] = av[1] + bv.y;
                v[2] = av[2] + bv.z; v[3] = av[3] + bv.w;
            } else {
                v[0] = av[0]; v[1] = av[1]; v[2] = av[2]; v[3] = av[3];
            }
            if (RELU) {
                #pragma unroll
                for (int r = 0; r < 4; r++) v[r] = fmaxf(v[r], 0.f);
            }
            if (Cf) {
                float4 o4; o4.x = v[0]; o4.y = v[1]; o4.z = v[2]; o4.w = v[3];
                *(float4*)&Cf[mrow + n0] = o4;
            }
            if (Cb) {
                uint2 pk;
                pk.x = f2bf(v[0]) | ((unsigned)f2bf(v[1]) << 16);
                pk.y = f2bf(v[2]) | ((unsigned)f2bf(v[3]) << 16);
                *(uint2*)&Cb[mrow + n0] = pk;
            }
        }
    }
}

// ---------------- attention: flash-style, block per (b, h, 128-row q-tile) ----------------
__global__ __launch_bounds__(256) void attn_kernel(const unsigned short* __restrict__ qkv,
                                                   unsigned short* __restrict__ ctx)
{
    __shared__ __align__(16) unsigned short sK [64 * SPLD];   // [t][d]
    __shared__ __align__(16) unsigned short sVt[64 * SPLD];   // [d][t]
    __shared__ __align__(16) unsigned short sP [128 * SPLD];  // [q][t] wave-private slabs

    const int tid  = threadIdx.x;
    const int blk  = blockIdx.x;
    const int qt   = blk & 3;
    const int hh   = (blk >> 2) & 15;
    const int b    = blk >> 6;
    const int w    = tid >> 6, lane = tid & 63;
    const int quad = lane >> 4, l16 = lane & 15;
    const size_t rowbase = (size_t)b * SS;
    const int LDQ = 3 * DD;

    short8 qf[2][2];
    #pragma unroll
    for (int m = 0; m < 2; m++) {
        const unsigned short* qrow =
            qkv + (rowbase + qt * 128 + w * 32 + m * 16 + l16) * (size_t)LDQ + hh * 64;
        #pragma unroll
        for (int kk = 0; kk < 2; kk++) {
            uint4 q4 = *(const uint4*)&qrow[kk * 32 + quad * 8];
            unsigned short* qs = (unsigned short*)&q4;
            short8 f;
            short* fp = (short*)&f;
            #pragma unroll
            for (int e = 0; e < 8; e++) fp[e] = (short)f2bf(bf2f(qs[e]) * 0.125f);
            qf[m][kk] = f;
        }
    }

    float l_part[2] = {0.f, 0.f};
    f32x4 o[2][4];
    #pragma unroll
    for (int m = 0; m < 2; m++)
        #pragma unroll
        for (int nt = 0; nt < 4; nt++) o[m][nt] = (f32x4){0.f, 0.f, 0.f, 0.f};

    for (int kt = 0; kt < 8; kt++) {
        __syncthreads();
        #pragma unroll
        for (int u = 0; u < 2; u++) {
            int c = tid * 2 + u;
            int r = c >> 3, cc = (c & 7) * 8;
            const size_t src = (rowbase + kt * 64 + r) * (size_t)LDQ + hh * 64 + cc;
            *(uint4*)&sK[r * SPLD + cc] = *(const uint4*)&qkv[src + DD];
            uint4 v4 = *(const uint4*)&qkv[src + 2 * DD];
            unsigned short* vs = (unsigned short*)&v4;
            #pragma unroll
            for (int e = 0; e < 8; e++) sVt[(cc + e) * SPLD + r] = vs[e];
        }
        __syncthreads();

        #pragma unroll
        for (int m = 0; m < 2; m++) {
            f32x4 s[4];
            #pragma unroll
            for (int ct = 0; ct < 4; ct++) s[ct] = (f32x4){0.f, 0.f, 0.f, 0.f};
            #pragma unroll
            for (int kk = 0; kk < 2; kk++)
                #pragma unroll
                for (int ct = 0; ct < 4; ct++) {
                    short8 kb = *(const short8*)&sK[(ct * 16 + l16) * SPLD + kk * 32 + quad * 8];
                    s[ct] = __builtin_amdgcn_mfma_f32_16x16x32_bf16(kb, qf[m][kk], s[ct], 0, 0, 0);
                }
            const int prow = (w * 32 + m * 16 + l16) * SPLD;
            float lp = 0.f;
            #pragma unroll
            for (int ct = 0; ct < 4; ct++) {
                float p0 = __expf(fminf(s[ct][0], 30.f));
                float p1 = __expf(fminf(s[ct][1], 30.f));
                float p2 = __expf(fminf(s[ct][2], 30.f));
                float p3 = __expf(fminf(s[ct][3], 30.f));
                lp += (p0 + p1) + (p2 + p3);
                uint2 pk;
                pk.x = f2bf(p0) | ((unsigned)f2bf(p1) << 16);
                pk.y = f2bf(p2) | ((unsigned)f2bf(p3) << 16);
                *(uint2*)&sP[prow + ct * 16 + quad * 4] = pk;
            }
            l_part[m] += lp;
        }

        #pragma unroll
        for (int m = 0; m < 2; m++)
            #pragma unroll
            for (int kk = 0; kk < 2; kk++) {
                short8 pa = *(const short8*)&sP[(w * 32 + m * 16 + l16) * SPLD + kk * 32 + quad * 8];
                #pragma unroll
                for (int nt = 0; nt < 4; nt++) {
                    short8 vb = *(const short8*)&sVt[(nt * 16 + l16) * SPLD + kk * 32 + quad * 8];
                    o[m][nt] = __builtin_amdgcn_mfma_f32_16x16x32_bf16(vb, pa, o[m][nt], 0, 0, 0);
                }
            }
    }

    #pragma unroll
    for (int m = 0; m < 2; m++) {
        float lt = l_part[m];
        lt += __shfl_xor(lt, 16);
        lt += __shfl_xor(lt, 32);
        float inv = 1.f / lt;
        const size_t crow = (rowbase + qt * 128 + w * 32 + m * 16 + l16) * DD + hh * 64;
        #pragma unroll
        for (int nt = 0; nt < 4; nt++) {
            uint2 pk;
            pk.x = f2bf(o[m][nt][0] * inv) | ((unsigned)f2bf(o[m][nt][1] * inv) << 16);
            pk.y = f2bf(o[m][nt][2] * inv) | ((unsigned)f2bf(o[m][nt][3] * inv) << 16);
            *(uint2*)&ctx[crow + nt * 16 + quad * 4] = pk;
        }
    }
}

// ---------------- layernorm (+ optional residual add), vectorized x4 ----------------
__global__ __launch_bounds__(256) void ln_kernel(
    unsigned short* __restrict__ hb, const unsigned short* __restrict__ add,
    const float* __restrict__ g, const float* __restrict__ beta)
{
    __shared__ float sred[4];
    const int t = blockIdx.x, tid = threadIdx.x;
    const int d0 = tid * 4;
    const size_t base = (size_t)t * DD + d0;
    float x[4];
    {
        uint2 hv = *(const uint2*)&hb[base];
        x[0] = bf2f(hv.x & 0xFFFF); x[1] = bf2f(hv.x >> 16);
        x[2] = bf2f(hv.y & 0xFFFF); x[3] = bf2f(hv.y >> 16);
    }
    if (add) {
        uint2 av = *(const uint2*)&add[base];
        x[0] += bf2f(av.x & 0xFFFF); x[1] += bf2f(av.x >> 16);
        x[2] += bf2f(av.y & 0xFFFF); x[3] += bf2f(av.y >> 16);
    }
    float s = (x[0] + x[1]) + (x[2] + x[3]);
    #pragma unroll
    for (int off = 32; off > 0; off >>= 1) s += __shfl_down(s, off);
    if ((tid & 63) == 0) sred[tid >> 6] = s;
    __syncthreads();
    float mu = (sred[0] + sred[1] + sred[2] + sred[3]) * (1.f / DD);
    __syncthreads();
    float vs = 0.f;
    #pragma unroll
    for (int i = 0; i < 4; i++) { float dx = x[i] - mu; vs += dx * dx; }
    #pragma unroll
    for (int off = 32; off > 0; off >>= 1) vs += __shfl_down(vs, off);
    if ((tid & 63) == 0) sred[tid >> 6] = vs;
    __syncthreads();
    float var = (sred[0] + sred[1] + sred[2] + sred[3]) * (1.f / DD);
    float inv = rsqrtf(var + 1e-5f);
    float4 gv = *(const float4*)&g[d0];
    float4 bv = *(const float4*)&beta[d0];
    float y0 = (x[0] - mu) * inv * gv.x + bv.x;
    float y1 = (x[1] - mu) * inv * gv.y + bv.y;
    float y2 = (x[2] - mu) * inv * gv.z + bv.z;
    float y3 = (x[3] - mu) * inv * gv.w + bv.w;
    uint2 pk;
    pk.x = f2bf(y0) | ((unsigned)f2bf(y1) << 16);
    pk.y = f2bf(y2) | ((unsigned)f2bf(y3) << 16);
    *(uint2*)&hb[base] = pk;
}

// ---------------- host-side GEMM dispatch helper ----------------
static void launch_gemm(bool relu, bool pre, const unsigned short* A,
                        const unsigned short* Wb, const float* Wf, const float* bias,
                        float* Cf, unsigned short* Cb, int M, int N, int K, hipStream_t s)
{
    if (pre && (M % 256 == 0) && (N % 256 == 0) && (K % 128 == 0) && N >= 1024) {
        dim3 g8(N / 256, M / 256);
        if (relu) gemm_bt8<true ><<<g8, 512, 0, s>>>(A, Wb, bias, Cf, Cb, M, N, K);
        else      gemm_bt8<false><<<g8, 512, 0, s>>>(A, Wb, bias, Cf, Cb, M, N, K);
        return;
    }
    dim3 g(N / 128, M / 128);
    if (pre) {
        if (relu) gemm_bt<true,  true ><<<g, 256, 0, s>>>(A, Wb, nullptr, bias, Cf, Cb, M, N, K);
        else      gemm_bt<false, true ><<<g, 256, 0, s>>>(A, Wb, nullptr, bias, Cf, Cb, M, N, K);
    } else {
        if (relu) gemm_bt<true,  false><<<g, 256, 0, s>>>(A, nullptr, Wf, bias, Cf, Cb, M, N, K);
        else      gemm_bt<false, false><<<g, 256, 0, s>>>(A, nullptr, Wf, bias, Cf, Cb, M, N, K);
    }
}

// ---------------- launcher ----------------
extern "C" void kernel_launch(void* const* d_in, const int* in_sizes, int n_in,
                              void* d_out, int out_size, void* d_ws, size_t ws_size,
                              hipStream_t stream)
{
    const float* x    = (const float*)d_in[0];
    const float* Wqkv = (const float*)d_in[1];
    const float* bqkv = (const float*)d_in[2];
    const float* Wo   = (const float*)d_in[3];
    const float* bo   = (const float*)d_in[4];
    const float* W1   = (const float*)d_in[5];
    const float* b1   = (const float*)d_in[6];
    const float* W2   = (const float*)d_in[7];
    const float* b2   = (const float*)d_in[8];
    const float* ln1g = (const float*)d_in[9];
    const float* ln1b = (const float*)d_in[10];
    const float* ln2g = (const float*)d_in[11];
    const float* ln2b = (const float*)d_in[12];
    const float* nfg  = (const float*)d_in[13];
    const float* nfb  = (const float*)d_in[14];
    const float* Wout = (const float*)d_in[15];
    const float* bout = (const float*)d_in[16];
    float* out = (float*)d_out;

    char* ws = (char*)d_ws;
    const size_t MB = 1024 * 1024;
    unsigned short* hb    = (unsigned short*)(ws + 0 * MB);
    unsigned short* qkvb  = (unsigned short*)(ws + 32 * MB);
    unsigned short* tmpb  = (unsigned short*)(ws + 96 * MB);
    unsigned short* ctxb  = (unsigned short*)(ws + 128 * MB);
    unsigned short* WqkvB = (unsigned short*)(ws + 160 * MB);
    unsigned short* W1B   = (unsigned short*)(ws + 184 * MB);
    unsigned short* W2B   = (unsigned short*)(ws + 200 * MB);
    unsigned short* WoB   = (unsigned short*)(ws + 216 * MB);
    unsigned short* WoutB = (unsigned short*)(ws + 224 * MB);

    const bool pre = ws_size >= 225 * MB;
    if (pre) {
        cvt_bf16<<<(LL * 3 * DD * DD / 4 + 255) / 256, 256, 0, stream>>>(Wqkv, WqkvB, LL * 3 * DD * DD);
        cvt_bf16<<<(LL * DFF * DD / 4 + 255) / 256, 256, 0, stream>>>(W1, W1B, LL * DFF * DD);
        cvt_bf16<<<(LL * DD * DFF / 4 + 255) / 256, 256, 0, stream>>>(W2, W2B, LL * DD * DFF);
        cvt_bf16<<<(LL * DD * DD / 4 + 255) / 256, 256, 0, stream>>>(Wo, WoB, LL * DD * DD);
        cvt_bf16<<<(DMEM * DD / 4 + 255) / 256, 256, 0, stream>>>(Wout, WoutB, DMEM * DD);
    }

    add_pe_kernel<<<NTOK * DD / 1024, 256, 0, stream>>>(x, hb);

    for (int l = 0; l < LL; l++) {
        launch_gemm(false, pre, hb, WqkvB + (size_t)l * 3 * DD * DD,
                    Wqkv + (size_t)l * 3 * DD * DD, bqkv + l * 3 * DD,
                    nullptr, qkvb, NTOK, 3 * DD, DD, stream);
        attn_kernel<<<BB * HH_ * 4, 256, 0, stream>>>(qkvb, ctxb);
        launch_gemm(false, pre, ctxb, WoB + (size_t)l * DD * DD,
                    Wo + (size_t)l * DD * DD, bo + l * DD,
                    nullptr, tmpb, NTOK, DD, DD, stream);
        ln_kernel<<<NTOK, 256, 0, stream>>>(hb, tmpb, ln1g + l * DD, ln1b + l * DD);
        launch_gemm(true, pre, hb, W1B + (size_t)l * DFF * DD,
                    W1 + (size_t)l * DFF * DD, b1 + l * DFF,
                    nullptr, qkvb, NTOK, DFF, DD, stream);
        launch_gemm(false, pre, qkvb, W2B + (size_t)l * DD * DFF,
                    W2 + (size_t)l * DD * DFF, b2 + l * DD,
                    nullptr, tmpb, NTOK, DD, DFF, stream);
        ln_kernel<<<NTOK, 256, 0, stream>>>(hb, tmpb, ln2g + l * DD, ln2b + l * DD);
    }
    ln_kernel<<<NTOK, 256, 0, stream>>>(hb, nullptr, nfg, nfb);
    launch_gemm(false, pre, hb, WoutB, Wout, bout, out, nullptr, NTOK, DMEM, DD, stream);
}

// Round 5
// 2025.474 us; speedup vs baseline: 1.0427x; 1.0427x over previous
//
#include <hip/hip_runtime.h>

// ---------------- constants ----------------
#define BB    32
#define SS    512
#define DD    1024
#define HH_   16
#define DH    64
#define LL    4
#define DFF   2048
#define DMEM  512
#define NTOK  (BB * SS)          // 16384
#define SPLD  74                 // padded LDS row stride (u16) for attn

typedef __attribute__((ext_vector_type(8))) short short8;
typedef __attribute__((ext_vector_type(4))) float f32x4;

__device__ __forceinline__ unsigned short f2bf(float x) {
    unsigned u = __float_as_uint(x);
    u = (u + 0x7FFFu + ((u >> 16) & 1u)) >> 16;   // RNE fp32->bf16
    return (unsigned short)u;
}
__device__ __forceinline__ float bf2f(unsigned short x) {
    return __uint_as_float(((unsigned)x) << 16);
}

// async global->LDS, 16 bytes per lane; LDS dest = wave-uniform base + lane*16
__device__ __forceinline__ void async16(const unsigned short* g, unsigned short* l) {
    __builtin_amdgcn_global_load_lds(
        (__attribute__((address_space(1))) void*)g,
        (__attribute__((address_space(3))) void*)l,
        16, 0, 0);
}

// ---------------- fp32 -> bf16 convert (vectorized x4) ----------------
__global__ void cvt_bf16(const float* __restrict__ in, unsigned short* __restrict__ out, int n) {
    int i4 = (blockIdx.x * 256 + threadIdx.x) * 4;
    if (i4 < n) {
        float4 v = *(const float4*)&in[i4];
        uint2 pk;
        pk.x = f2bf(v.x) | ((unsigned)f2bf(v.y) << 16);
        pk.y = f2bf(v.z) | ((unsigned)f2bf(v.w) << 16);
        *(uint2*)&out[i4] = pk;
    }
}

// ---------------- h = x + PE -> bf16 residual stream (vectorized x4) ----------------
__global__ void add_pe_kernel(const float* __restrict__ x,
                              unsigned short* __restrict__ hb) {
    int i4 = (blockIdx.x * 256 + threadIdx.x) * 4;   // 16M elems / 4
    int d = i4 & (DD - 1);                           // multiple of 4
    int t = i4 >> 10;
    int s = t & (SS - 1);
    const float c = -9.210340371976184f / (float)DD;
    float f0 = __expf((float)d * c);
    float f2 = __expf((float)(d + 2) * c);
    float a0 = (float)s * f0, a2 = (float)s * f2;
    float4 xv = *(const float4*)&x[i4];
    uint2 pk;
    pk.x = f2bf(xv.x + __sinf(a0)) | ((unsigned)f2bf(xv.y + __cosf(a0)) << 16);
    pk.y = f2bf(xv.z + __sinf(a2)) | ((unsigned)f2bf(xv.w + __cosf(a2)) << 16);
    *(uint2*)&hb[i4] = pk;
}

// ================== 256x256 8-phase GEMM (T1+T2+T3/T4+T5), bf16 weights ==================
// C[M,N] = A[M,K] * W[N,K]^T + bias. 512 threads = 8 waves (2M x 4N), per-wave 128x64.
// BK=64 per K-tile, 2 K-tiles (buf0/buf1) double-buffered = 128 KiB LDS.
// Staging: global_load_lds, linear LDS dest, INVERSE-swizzled global source;
// reads XOR-swizzle the 16B chunk index by (row&7) -> conflict-free per 8-lane phase.
// DEEP PREFETCH (r5): buffer X's refill (K-tile t+2) issues during X's own compute
// half-iter at phC (X.B, after its last reader phB+BAR) and phD (X.A, after phC+BAR).
// vmcnt(8) at phD drains loads issued 4-5 phases (~1000 cy) earlier -> covers HBM latency.
// setprio(1) around MFMA clusters. XCD-swizzled blockIdx for A-panel L2 residency.
#define BAR   __builtin_amdgcn_s_barrier()
#define LGKM0 do { asm volatile("s_waitcnt lgkmcnt(0)" ::: "memory"); \
                   __builtin_amdgcn_sched_barrier(0); } while (0)
#define VMC8  asm volatile("s_waitcnt vmcnt(8)" ::: "memory")

// stage one 128-row half-tile (2 x global_load_lds per wave):
// OP: 0=A, 1=W. rows (HALF*128 + wid*16 .. +15), global chunk = (lane&7)^(lane>>3)
#define STAGE(BUF, OP, HALFI, KS) do {                                          \
    const unsigned short* _g = (OP) ? Wb : A;                                   \
    const size_t _gr = ((OP) ? Brow0 : Arow0) + (HALFI) * 128 + wid * 16 + l8;  \
    unsigned short* _d = &lds[BUF][OP][(((HALFI) * 128 + wid * 16)) * 64];      \
    const int _ks = (KS);                                                       \
    async16(&_g[_gr * (size_t)K + _ks + cl8], _d);                              \
    async16(&_g[(_gr + 8) * (size_t)K + _ks + cl8], _d + 8 * 64);               \
} while (0)

// one half-iteration = 4 phases computing K-tile in buf CUR; refills CUR with KSR:
//  phA: read A[m0-3],B[n0-1];                      mfma (m0-3 x n0-1)
//  phB: read B[n2-3];                              mfma (m0-3 x n2-3)
//  phC: read A[m4-7]; stage CUR.B h0+h1 @KSR;      mfma (m4-7 x n2-3)
//  phD: stage CUR.A h0+h1 @KSR; vmcnt(8);          mfma (m4-7 x n0-1)
#define HALF_ITER(CUR, KSR) {                                                   \
    short8 afr[4][2], b01[2][2], b23[2][2];                                     \
    _Pragma("unroll") for (int m = 0; m < 4; m++) {                             \
        afr[m][0] = *(const short8*)&lds[CUR][0][aro + m * 1024 + cb0];         \
        afr[m][1] = *(const short8*)&lds[CUR][0][aro + m * 1024 + cb1]; }       \
    _Pragma("unroll") for (int n = 0; n < 2; n++) {                             \
        b01[n][0] = *(const short8*)&lds[CUR][1][bro + n * 1024 + cb0];         \
        b01[n][1] = *(const short8*)&lds[CUR][1][bro + n * 1024 + cb1]; }       \
    BAR; LGKM0;                                                                 \
    __builtin_amdgcn_s_setprio(1);                                              \
    _Pragma("unroll") for (int m = 0; m < 4; m++)                               \
        _Pragma("unroll") for (int n = 0; n < 2; n++) {                         \
            acc[m][n] = __builtin_amdgcn_mfma_f32_16x16x32_bf16(b01[n][0], afr[m][0], acc[m][n], 0, 0, 0); \
            acc[m][n] = __builtin_amdgcn_mfma_f32_16x16x32_bf16(b01[n][1], afr[m][1], acc[m][n], 0, 0, 0); } \
    __builtin_amdgcn_s_setprio(0);                                              \
    BAR;                                                                        \
    _Pragma("unroll") for (int n = 0; n < 2; n++) {                             \
        b23[n][0] = *(const short8*)&lds[CUR][1][bro + (n + 2) * 1024 + cb0];   \
        b23[n][1] = *(const short8*)&lds[CUR][1][bro + (n + 2) * 1024 + cb1]; } \
    BAR; LGKM0;                                                                 \
    __builtin_amdgcn_s_setprio(1);                                              \
    _Pragma("unroll") for (int m = 0; m < 4; m++)                               \
        _Pragma("unroll") for (int n = 0; n < 2; n++) {                         \
            acc[m][n + 2] = __builtin_amdgcn_mfma_f32_16x16x32_bf16(b23[n][0], afr[m][0], acc[m][n + 2], 0, 0, 0); \
            acc[m][n + 2] = __builtin_amdgcn_mfma_f32_16x16x32_bf16(b23[n][1], afr[m][1], acc[m][n + 2], 0, 0, 0); } \
    __builtin_amdgcn_s_setprio(0);                                              \
    BAR;                                                                        \
    _Pragma("unroll") for (int m = 0; m < 4; m++) {                             \
        afr[m][0] = *(const short8*)&lds[CUR][0][aro + (m + 4) * 1024 + cb0];   \
        afr[m][1] = *(const short8*)&lds[CUR][0][aro + (m + 4) * 1024 + cb1]; } \
    STAGE(CUR, 1, 0, KSR);                                                      \
    STAGE(CUR, 1, 1, KSR);                                                      \
    BAR; LGKM0;                                                                 \
    __builtin_amdgcn_s_setprio(1);                                              \
    _Pragma("unroll") for (int m = 0; m < 4; m++)                               \
        _Pragma("unroll") for (int n = 0; n < 2; n++) {                         \
            acc[m + 4][n + 2] = __builtin_amdgcn_mfma_f32_16x16x32_bf16(b23[n][0], afr[m][0], acc[m + 4][n + 2], 0, 0, 0); \
            acc[m + 4][n + 2] = __builtin_amdgcn_mfma_f32_16x16x32_bf16(b23[n][1], afr[m][1], acc[m + 4][n + 2], 0, 0, 0); } \
    __builtin_amdgcn_s_setprio(0);                                              \
    BAR;                                                                        \
    STAGE(CUR, 0, 0, KSR);                                                      \
    STAGE(CUR, 0, 1, KSR);                                                      \
    VMC8;                                                                       \
    BAR;                                                                        \
    __builtin_amdgcn_s_setprio(1);                                              \
    _Pragma("unroll") for (int m = 0; m < 4; m++)                               \
        _Pragma("unroll") for (int n = 0; n < 2; n++) {                         \
            acc[m + 4][n] = __builtin_amdgcn_mfma_f32_16x16x32_bf16(b01[n][0], afr[m][0], acc[m + 4][n], 0, 0, 0); \
            acc[m + 4][n] = __builtin_amdgcn_mfma_f32_16x16x32_bf16(b01[n][1], afr[m][1], acc[m + 4][n], 0, 0, 0); } \
    __builtin_amdgcn_s_setprio(0);                                              \
    BAR;                                                                        \
}

template<bool RELU>
__global__ __launch_bounds__(512, 2) void gemm_bt8(
    const unsigned short* __restrict__ A,
    const unsigned short* __restrict__ Wb,
    const float* __restrict__ bias,
    float* __restrict__ Cf, unsigned short* __restrict__ Cb,
    int M, int N, int K)
{
    __shared__ __align__(16) unsigned short lds[2][2][256 * 64];   // [buf][A/W][row*64+col]
    const int tid  = threadIdx.x;
    const int wid  = tid >> 6, lane = tid & 63;
    const int wm   = wid >> 2, wn = wid & 3;        // 2 x 4 wave grid
    const int quad = lane >> 4, l16 = lane & 15;
    const int l8   = lane >> 3;                     // staging: row within 8-row segment
    const int cl8  = (((lane & 7) ^ l8) & 7) * 8;   // staging: global chunk (u16 units)

    // ---- XCD-aware block swizzle (T1): contiguous logical chunk per XCD ----
    const int nwgx = gridDim.x;
    const int nwg  = nwgx * (int)gridDim.y;
    int orig = blockIdx.y * nwgx + blockIdx.x;
    int swid = ((nwg & 7) == 0) ? ((orig & 7) * (nwg >> 3) + (orig >> 3)) : orig;
    const int bm = swid / nwgx, bn = swid % nwgx;
    const size_t Arow0 = (size_t)bm * 256, Brow0 = (size_t)bn * 256;

    // read-side swizzled column offsets (u16) for kk=0,1: chunk = (kk*4+quad) ^ (l16&7)
    const int swz = l16 & 7;
    const int cb0 = ((quad) ^ swz) * 8;
    const int cb1 = ((4 + quad) ^ swz) * 8;
    // per-wave row bases (u16 index): + m*1024 / n*1024 + cb
    const int aro = (wm * 128 + l16) * 64;
    const int bro = (wn * 64 + l16) * 64;

    f32x4 acc[8][4];
    #pragma unroll
    for (int i = 0; i < 8; i++)
        #pragma unroll
        for (int j = 0; j < 4; j++) acc[i][j] = (f32x4){0.f, 0.f, 0.f, 0.f};

    // ---- prologue: fully stage buf0 (ktile 0) then buf1 (ktile 1); wait oldest 8 ----
    STAGE(0, 1, 0, 0);  STAGE(0, 1, 1, 0);
    STAGE(0, 0, 0, 0);  STAGE(0, 0, 1, 0);
    STAGE(1, 1, 0, 64); STAGE(1, 1, 1, 64);
    STAGE(1, 0, 0, 64); STAGE(1, 0, 1, 64);
    VMC8;
    BAR;

    const int NT = K >> 6;                  // K/64 K-tiles (even: K%128==0)
    for (int t = 0; t < NT; t += 2) {
        const int ks0 = ((t + 2 < NT) ? (t + 2) : (NT - 1)) * 64;  // buf0 refill (dead if tail)
        const int ks1 = ((t + 3 < NT) ? (t + 3) : (NT - 1)) * 64;  // buf1 refill
        HALF_ITER(0, ks0)
        HALF_ITER(1, ks1)
    }

    // ---- epilogue (same fragment convention as verified m97 kernel) ----
    #pragma unroll
    for (int i = 0; i < 8; i++) {
        const size_t mrow = (size_t)(bm * 256 + wm * 128 + i * 16 + l16) * N;
        #pragma unroll
        for (int j = 0; j < 4; j++) {
            int n0 = bn * 256 + wn * 64 + j * 16 + quad * 4;
            f32x4 av = acc[i][j];
            float v[4];
            if (bias) {
                float4 bv = *(const float4*)&bias[n0];
                v[0] = av[0] + bv.x; v[1] = av[1] + bv.y;
                v[2] = av[2] + bv.z; v[3] = av[3] + bv.w;
            } else {
                v[0] = av[0]; v[1] = av[1]; v[2] = av[2]; v[3] = av[3];
            }
            if (RELU) {
                #pragma unroll
                for (int r = 0; r < 4; r++) v[r] = fmaxf(v[r], 0.f);
            }
            if (Cf) {
                float4 o4; o4.x = v[0]; o4.y = v[1]; o4.z = v[2]; o4.w = v[3];
                *(float4*)&Cf[mrow + n0] = o4;
            }
            if (Cb) {
                uint2 pk;
                pk.x = f2bf(v[0]) | ((unsigned)f2bf(v[1]) << 16);
                pk.y = f2bf(v[2]) | ((unsigned)f2bf(v[3]) << 16);
                *(uint2*)&Cb[mrow + n0] = pk;
            }
        }
    }
}

// ---------------- bf16 GEMM (m97 structure): fallback + N<1024 shapes ----------------
template<bool RELU, bool WPRE>
__global__ __launch_bounds__(256) void gemm_bt(
    const unsigned short* __restrict__ A,
    const unsigned short* __restrict__ Wb,
    const float* __restrict__ Wf,
    const float* __restrict__ bias,
    float* __restrict__ Cf, unsigned short* __restrict__ Cb,
    int M, int N, int K)
{
    __shared__ __align__(16) unsigned short As[128 * 32];
    __shared__ __align__(16) unsigned short Bs[128 * 32];
    const int tid  = threadIdx.x;
    const int bm   = blockIdx.y, bn = blockIdx.x;
    const int w    = tid >> 6, lane = tid & 63;
    const int wm   = (w >> 1) * 64, wn = (w & 1) * 64;
    const int quad = lane >> 4, l16 = lane & 15;

    f32x4 acc[4][4];
    #pragma unroll
    for (int i = 0; i < 4; i++)
        #pragma unroll
        for (int j = 0; j < 4; j++) acc[i][j] = (f32x4){0.f, 0.f, 0.f, 0.f};

    const int rlane = lane >> 2, clane = (lane & 3) * 8;

    for (int k0 = 0; k0 < K; k0 += 32) {
        __syncthreads();
        if (WPRE) {
            #pragma unroll
            for (int i = 0; i < 2; i++) {
                int j = w * 2 + i;
                async16(&A [(size_t)(bm * 128 + j * 16 + rlane) * K + k0 + clane], &As[j * 512]);
                async16(&Wb[(size_t)(bn * 128 + j * 16 + rlane) * K + k0 + clane], &Bs[j * 512]);
            }
        } else {
            #pragma unroll
            for (int u = 0; u < 2; u++) {
                int c = tid * 2 + u;
                int row = c >> 2, cc = (c & 3) * 8;
                *(uint4*)&As[row * 32 + cc] =
                    *(const uint4*)&A[(size_t)(bm * 128 + row) * K + k0 + cc];
                const float* wp = &Wf[(size_t)(bn * 128 + row) * K + k0 + cc];
                float4 w0 = *(const float4*)wp;
                float4 w1 = *(const float4*)(wp + 4);
                uint4 pk;
                pk.x = ((unsigned)f2bf(w0.y) << 16) | f2bf(w0.x);
                pk.y = ((unsigned)f2bf(w0.w) << 16) | f2bf(w0.z);
                pk.z = ((unsigned)f2bf(w1.y) << 16) | f2bf(w1.x);
                pk.w = ((unsigned)f2bf(w1.w) << 16) | f2bf(w1.z);
                *(uint4*)&Bs[row * 32 + cc] = pk;
            }
        }
        __syncthreads();
        short8 af[4], bfr[4];
        #pragma unroll
        for (int i = 0; i < 4; i++)
            af[i] = *(const short8*)&As[(wm + i * 16 + l16) * 32 + quad * 8];
        #pragma unroll
        for (int j = 0; j < 4; j++)
            bfr[j] = *(const short8*)&Bs[(wn + j * 16 + l16) * 32 + quad * 8];
        #pragma unroll
        for (int i = 0; i < 4; i++)
            #pragma unroll
            for (int j = 0; j < 4; j++)
                acc[i][j] = __builtin_amdgcn_mfma_f32_16x16x32_bf16(bfr[j], af[i], acc[i][j], 0, 0, 0);
    }

    #pragma unroll
    for (int i = 0; i < 4; i++) {
        const size_t mrow = (size_t)(bm * 128 + wm + i * 16 + l16) * N;
        #pragma unroll
        for (int j = 0; j < 4; j++) {
            int n0 = bn * 128 + wn + j * 16 + quad * 4;
            f32x4 av = acc[i][j];
            float v[4];
            if (bias) {
                float4 bv = *(const float4*)&bias[n0];
                v[0] = av[0] + bv.x; v[1] = av[1] + bv.y;
                v[2] = av[2] + bv.z; v[3] = av[3] + bv.w;
            } else {
                v[0] = av[0]; v[1] = av[1]; v[2] = av[2]; v[3] = av[3];
            }
            if (RELU) {
                #pragma unroll
                for (int r = 0; r < 4; r++) v[r] = fmaxf(v[r], 0.f);
            }
            if (Cf) {
                float4 o4; o4.x = v[0]; o4.y = v[1]; o4.z = v[2]; o4.w = v[3];
                *(float4*)&Cf[mrow + n0] = o4;
            }
            if (Cb) {
                uint2 pk;
                pk.x = f2bf(v[0]) | ((unsigned)f2bf(v[1]) << 16);
                pk.y = f2bf(v[2]) | ((unsigned)f2bf(v[3]) << 16);
                *(uint2*)&Cb[mrow + n0] = pk;
            }
        }
    }
}

// ---------------- attention: flash-style, block per (b, h, 128-row q-tile) ----------------
__global__ __launch_bounds__(256) void attn_kernel(const unsigned short* __restrict__ qkv,
                                                   unsigned short* __restrict__ ctx)
{
    __shared__ __align__(16) unsigned short sK [64 * SPLD];   // [t][d]
    __shared__ __align__(16) unsigned short sVt[64 * SPLD];   // [d][t]
    __shared__ __align__(16) unsigned short sP [128 * SPLD];  // [q][t] wave-private slabs

    const int tid  = threadIdx.x;
    const int blk  = blockIdx.x;
    const int qt   = blk & 3;
    const int hh   = (blk >> 2) & 15;
    const int b    = blk >> 6;
    const int w    = tid >> 6, lane = tid & 63;
    const int quad = lane >> 4, l16 = lane & 15;
    const size_t rowbase = (size_t)b * SS;
    const int LDQ = 3 * DD;

    short8 qf[2][2];
    #pragma unroll
    for (int m = 0; m < 2; m++) {
        const unsigned short* qrow =
            qkv + (rowbase + qt * 128 + w * 32 + m * 16 + l16) * (size_t)LDQ + hh * 64;
        #pragma unroll
        for (int kk = 0; kk < 2; kk++) {
            uint4 q4 = *(const uint4*)&qrow[kk * 32 + quad * 8];
            unsigned short* qs = (unsigned short*)&q4;
            short8 f;
            short* fp = (short*)&f;
            #pragma unroll
            for (int e = 0; e < 8; e++) fp[e] = (short)f2bf(bf2f(qs[e]) * 0.125f);
            qf[m][kk] = f;
        }
    }

    float l_part[2] = {0.f, 0.f};
    f32x4 o[2][4];
    #pragma unroll
    for (int m = 0; m < 2; m++)
        #pragma unroll
        for (int nt = 0; nt < 4; nt++) o[m][nt] = (f32x4){0.f, 0.f, 0.f, 0.f};

    for (int kt = 0; kt < 8; kt++) {
        __syncthreads();
        #pragma unroll
        for (int u = 0; u < 2; u++) {
            int c = tid * 2 + u;
            int r = c >> 3, cc = (c & 7) * 8;
            const size_t src = (rowbase + kt * 64 + r) * (size_t)LDQ + hh * 64 + cc;
            *(uint4*)&sK[r * SPLD + cc] = *(const uint4*)&qkv[src + DD];
            uint4 v4 = *(const uint4*)&qkv[src + 2 * DD];
            unsigned short* vs = (unsigned short*)&v4;
            #pragma unroll
            for (int e = 0; e < 8; e++) sVt[(cc + e) * SPLD + r] = vs[e];
        }
        __syncthreads();

        #pragma unroll
        for (int m = 0; m < 2; m++) {
            f32x4 s[4];
            #pragma unroll
            for (int ct = 0; ct < 4; ct++) s[ct] = (f32x4){0.f, 0.f, 0.f, 0.f};
            #pragma unroll
            for (int kk = 0; kk < 2; kk++)
                #pragma unroll
                for (int ct = 0; ct < 4; ct++) {
                    short8 kb = *(const short8*)&sK[(ct * 16 + l16) * SPLD + kk * 32 + quad * 8];
                    s[ct] = __builtin_amdgcn_mfma_f32_16x16x32_bf16(kb, qf[m][kk], s[ct], 0, 0, 0);
                }
            const int prow = (w * 32 + m * 16 + l16) * SPLD;
            float lp = 0.f;
            #pragma unroll
            for (int ct = 0; ct < 4; ct++) {
                float p0 = __expf(fminf(s[ct][0], 30.f));
                float p1 = __expf(fminf(s[ct][1], 30.f));
                float p2 = __expf(fminf(s[ct][2], 30.f));
                float p3 = __expf(fminf(s[ct][3], 30.f));
                lp += (p0 + p1) + (p2 + p3);
                uint2 pk;
                pk.x = f2bf(p0) | ((unsigned)f2bf(p1) << 16);
                pk.y = f2bf(p2) | ((unsigned)f2bf(p3) << 16);
                *(uint2*)&sP[prow + ct * 16 + quad * 4] = pk;
            }
            l_part[m] += lp;
        }

        #pragma unroll
        for (int m = 0; m < 2; m++)
            #pragma unroll
            for (int kk = 0; kk < 2; kk++) {
                short8 pa = *(const short8*)&sP[(w * 32 + m * 16 + l16) * SPLD + kk * 32 + quad * 8];
                #pragma unroll
                for (int nt = 0; nt < 4; nt++) {
                    short8 vb = *(const short8*)&sVt[(nt * 16 + l16) * SPLD + kk * 32 + quad * 8];
                    o[m][nt] = __builtin_amdgcn_mfma_f32_16x16x32_bf16(vb, pa, o[m][nt], 0, 0, 0);
                }
            }
    }

    #pragma unroll
    for (int m = 0; m < 2; m++) {
        float lt = l_part[m];
        lt += __shfl_xor(lt, 16);
        lt += __shfl_xor(lt, 32);
        float inv = 1.f / lt;
        const size_t crow = (rowbase + qt * 128 + w * 32 + m * 16 + l16) * DD + hh * 64;
        #pragma unroll
        for (int nt = 0; nt < 4; nt++) {
            uint2 pk;
            pk.x = f2bf(o[m][nt][0] * inv) | ((unsigned)f2bf(o[m][nt][1] * inv) << 16);
            pk.y = f2bf(o[m][nt][2] * inv) | ((unsigned)f2bf(o[m][nt][3] * inv) << 16);
            *(uint2*)&ctx[crow + nt * 16 + quad * 4] = pk;
        }
    }
}

// ---------------- layernorm (+ optional residual add), vectorized x4 ----------------
__global__ __launch_bounds__(256) void ln_kernel(
    unsigned short* __restrict__ hb, const unsigned short* __restrict__ add,
    const float* __restrict__ g, const float* __restrict__ beta)
{
    __shared__ float sred[4];
    const int t = blockIdx.x, tid = threadIdx.x;
    const int d0 = tid * 4;
    const size_t base = (size_t)t * DD + d0;
    float x[4];
    {
        uint2 hv = *(const uint2*)&hb[base];
        x[0] = bf2f(hv.x & 0xFFFF); x[1] = bf2f(hv.x >> 16);
        x[2] = bf2f(hv.y & 0xFFFF); x[3] = bf2f(hv.y >> 16);
    }
    if (add) {
        uint2 av = *(const uint2*)&add[base];
        x[0] += bf2f(av.x & 0xFFFF); x[1] += bf2f(av.x >> 16);
        x[2] += bf2f(av.y & 0xFFFF); x[3] += bf2f(av.y >> 16);
    }
    float s = (x[0] + x[1]) + (x[2] + x[3]);
    #pragma unroll
    for (int off = 32; off > 0; off >>= 1) s += __shfl_down(s, off);
    if ((tid & 63) == 0) sred[tid >> 6] = s;
    __syncthreads();
    float mu = (sred[0] + sred[1] + sred[2] + sred[3]) * (1.f / DD);
    __syncthreads();
    float vs = 0.f;
    #pragma unroll
    for (int i = 0; i < 4; i++) { float dx = x[i] - mu; vs += dx * dx; }
    #pragma unroll
    for (int off = 32; off > 0; off >>= 1) vs += __shfl_down(vs, off);
    if ((tid & 63) == 0) sred[tid >> 6] = vs;
    __syncthreads();
    float var = (sred[0] + sred[1] + sred[2] + sred[3]) * (1.f / DD);
    float inv = rsqrtf(var + 1e-5f);
    float4 gv = *(const float4*)&g[d0];
    float4 bv = *(const float4*)&beta[d0];
    float y0 = (x[0] - mu) * inv * gv.x + bv.x;
    float y1 = (x[1] - mu) * inv * gv.y + bv.y;
    float y2 = (x[2] - mu) * inv * gv.z + bv.z;
    float y3 = (x[3] - mu) * inv * gv.w + bv.w;
    uint2 pk;
    pk.x = f2bf(y0) | ((unsigned)f2bf(y1) << 16);
    pk.y = f2bf(y2) | ((unsigned)f2bf(y3) << 16);
    *(uint2*)&hb[base] = pk;
}

// ---------------- host-side GEMM dispatch helper ----------------
static void launch_gemm(bool relu, bool pre, const unsigned short* A,
                        const unsigned short* Wb, const float* Wf, const float* bias,
                        float* Cf, unsigned short* Cb, int M, int N, int K, hipStream_t s)
{
    if (pre && (M % 256 == 0) && (N % 256 == 0) && (K % 128 == 0) && N >= 1024) {
        dim3 g8(N / 256, M / 256);
        if (relu) gemm_bt8<true ><<<g8, 512, 0, s>>>(A, Wb, bias, Cf, Cb, M, N, K);
        else      gemm_bt8<false><<<g8, 512, 0, s>>>(A, Wb, bias, Cf, Cb, M, N, K);
        return;
    }
    dim3 g(N / 128, M / 128);
    if (pre) {
        if (relu) gemm_bt<true,  true ><<<g, 256, 0, s>>>(A, Wb, nullptr, bias, Cf, Cb, M, N, K);
        else      gemm_bt<false, true ><<<g, 256, 0, s>>>(A, Wb, nullptr, bias, Cf, Cb, M, N, K);
    } else {
        if (relu) gemm_bt<true,  false><<<g, 256, 0, s>>>(A, nullptr, Wf, bias, Cf, Cb, M, N, K);
        else      gemm_bt<false, false><<<g, 256, 0, s>>>(A, nullptr, Wf, bias, Cf, Cb, M, N, K);
    }
}

// ---------------- launcher ----------------
extern "C" void kernel_launch(void* const* d_in, const int* in_sizes, int n_in,
                              void* d_out, int out_size, void* d_ws, size_t ws_size,
                              hipStream_t stream)
{
    const float* x    = (const float*)d_in[0];
    const float* Wqkv = (const float*)d_in[1];
    const float* bqkv = (const float*)d_in[2];
    const float* Wo   = (const float*)d_in[3];
    const float* bo   = (const float*)d_in[4];
    const float* W1   = (const float*)d_in[5];
    const float* b1   = (const float*)d_in[6];
    const float* W2   = (const float*)d_in[7];
    const float* b2   = (const float*)d_in[8];
    const float* ln1g = (const float*)d_in[9];
    const float* ln1b = (const float*)d_in[10];
    const float* ln2g = (const float*)d_in[11];
    const float* ln2b = (const float*)d_in[12];
    const float* nfg  = (const float*)d_in[13];
    const float* nfb  = (const float*)d_in[14];
    const float* Wout = (const float*)d_in[15];
    const float* bout = (const float*)d_in[16];
    float* out = (float*)d_out;

    char* ws = (char*)d_ws;
    const size_t MB = 1024 * 1024;
    unsigned short* hb    = (unsigned short*)(ws + 0 * MB);
    unsigned short* qkvb  = (unsigned short*)(ws + 32 * MB);
    unsigned short* tmpb  = (unsigned short*)(ws + 96 * MB);
    unsigned short* ctxb  = (unsigned short*)(ws + 128 * MB);
    unsigned short* WqkvB = (unsigned short*)(ws + 160 * MB);
    unsigned short* W1B   = (unsigned short*)(ws + 184 * MB);
    unsigned short* W2B   = (unsigned short*)(ws + 200 * MB);
    unsigned short* WoB   = (unsigned short*)(ws + 216 * MB);
    unsigned short* WoutB = (unsigned short*)(ws + 224 * MB);

    const bool pre = ws_size >= 225 * MB;
    if (pre) {
        cvt_bf16<<<(LL * 3 * DD * DD / 4 + 255) / 256, 256, 0, stream>>>(Wqkv, WqkvB, LL * 3 * DD * DD);
        cvt_bf16<<<(LL * DFF * DD / 4 + 255) / 256, 256, 0, stream>>>(W1, W1B, LL * DFF * DD);
        cvt_bf16<<<(LL * DD * DFF / 4 + 255) / 256, 256, 0, stream>>>(W2, W2B, LL * DD * DFF);
        cvt_bf16<<<(LL * DD * DD / 4 + 255) / 256, 256, 0, stream>>>(Wo, WoB, LL * DD * DD);
        cvt_bf16<<<(DMEM * DD / 4 + 255) / 256, 256, 0, stream>>>(Wout, WoutB, DMEM * DD);
    }

    add_pe_kernel<<<NTOK * DD / 1024, 256, 0, stream>>>(x, hb);

    for (int l = 0; l < LL; l++) {
        launch_gemm(false, pre, hb, WqkvB + (size_t)l * 3 * DD * DD,
                    Wqkv + (size_t)l * 3 * DD * DD, bqkv + l * 3 * DD,
                    nullptr, qkvb, NTOK, 3 * DD, DD, stream);
        attn_kernel<<<BB * HH_ * 4, 256, 0, stream>>>(qkvb, ctxb);
        launch_gemm(false, pre, ctxb, WoB + (size_t)l * DD * DD,
                    Wo + (size_t)l * DD * DD, bo + l * DD,
                    nullptr, tmpb, NTOK, DD, DD, stream);
        ln_kernel<<<NTOK, 256, 0, stream>>>(hb, tmpb, ln1g + l * DD, ln1b + l * DD);
        launch_gemm(true, pre, hb, W1B + (size_t)l * DFF * DD,
                    W1 + (size_t)l * DFF * DD, b1 + l * DFF,
                    nullptr, qkvb, NTOK, DFF, DD, stream);
        launch_gemm(false, pre, qkvb, W2B + (size_t)l * DD * DFF,
                    W2 + (size_t)l * DD * DFF, b2 + l * DD,
                    nullptr, tmpb, NTOK, DD, DFF, stream);
        ln_kernel<<<NTOK, 256, 0, stream>>>(hb, tmpb, ln2g + l * DD, ln2b + l * DD);
    }
    ln_kernel<<<NTOK, 256, 0, stream>>>(hb, nullptr, nfg, nfb);
    launch_gemm(false, pre, hb, WoutB, Wout, bout, out, nullptr, NTOK, DMEM, DD, stream);
}